// Round 1
// baseline (95.074 us; speedup 1.0000x reference)
//
#include <hip/hip_runtime.h>
#include <hip/hip_bf16.h>
#include <math.h>

// Problem constants (from reference):
//   B=128, S=1024, D1=64 (SIZE1), N=2048, D0=512 (SIZE0)
#define B_   128
#define S_   1024
#define D1_  64
#define N_   2048
#define D0_  512

// -----------------------------------------------------------------------------
// Kernel 0: v[b,s] = sum_d enc[b, current_index, d] * W[d, s]
// Grid: B_ blocks, D0_ threads. W reads are coalesced across threads and
// L2-resident after the first block. Bias term is dropped: it adds a
// per-row constant to the logits, which cancels exactly in softmax.
// -----------------------------------------------------------------------------
__global__ __launch_bounds__(D0_) void prep_kernel(
    const float* __restrict__ enc, const int* __restrict__ cur_idx,
    const float* __restrict__ W, float* __restrict__ v)
{
    __shared__ float temp[D1_];
    const int b = blockIdx.x;
    const int t = threadIdx.x;           // 0..511
    const int ci = *cur_idx;
    if (t < D1_) {
        temp[t] = enc[(size_t)b * (S_ * D1_) + (size_t)ci * D1_ + t];
    }
    __syncthreads();
    float acc = 0.f;
#pragma unroll
    for (int d = 0; d < D1_; ++d) {
        acc += temp[d] * W[d * D0_ + t];
    }
    v[b * D0_ + t] = acc;
}

// -----------------------------------------------------------------------------
// Kernel 1: logits[b,n] = dot(neighbor[b,n,:], v[b,:])  (512-long dot)
// One 64-lane wave per (b,n) row: each lane loads 2 float4 (coalesced,
// 1 KiB / instruction / wave), FMAs against v (L2-resident, 256 KB total),
// then 6-step butterfly shuffle reduction. Writes logits into d_out.
// Block = 256 threads = 4 waves = 4 rows; grid = B_*N_/4 = 65536 blocks.
// -----------------------------------------------------------------------------
__global__ __launch_bounds__(256) void logits_kernel(
    const float* __restrict__ nb, const float* __restrict__ v,
    float* __restrict__ out)
{
    const int wave = threadIdx.x >> 6;          // 0..3
    const int lane = threadIdx.x & 63;
    const size_t row = (size_t)blockIdx.x * 4 + wave;   // 0 .. B_*N_-1
    const int b = (int)(row >> 11);             // row / N_
    const float4* __restrict__ r = (const float4*)(nb + row * D0_);
    const float4* __restrict__ vv = (const float4*)(v + (size_t)b * D0_);

    float4 r0 = r[lane];
    float4 r1 = r[lane + 64];
    float4 v0 = vv[lane];
    float4 v1 = vv[lane + 64];

    float s = r0.x * v0.x + r0.y * v0.y + r0.z * v0.z + r0.w * v0.w
            + r1.x * v1.x + r1.y * v1.y + r1.z * v1.z + r1.w * v1.w;

#pragma unroll
    for (int off = 32; off; off >>= 1) s += __shfl_xor(s, off);

    if (lane == 0) out[row] = s;
}

// -----------------------------------------------------------------------------
// Kernel 2: in-place row softmax over N_=2048 elements. 128 blocks (one per
// batch) x 256 threads; each thread owns 8 elements. Two block reductions
// (max, sum) via wave shuffle + tiny LDS.
// -----------------------------------------------------------------------------
__global__ __launch_bounds__(256) void softmax_kernel(float* __restrict__ out)
{
    float* row = out + (size_t)blockIdx.x * N_;
    const int t = threadIdx.x;
    const int wave = t >> 6, lane = t & 63;

    float vals[8];
    float m = -INFINITY;
#pragma unroll
    for (int i = 0; i < 8; ++i) {
        vals[i] = row[t + i * 256];
        m = fmaxf(m, vals[i]);
    }
#pragma unroll
    for (int off = 32; off; off >>= 1) m = fmaxf(m, __shfl_xor(m, off));

    __shared__ float redm[4];
    __shared__ float reds[4];
    if (lane == 0) redm[wave] = m;
    __syncthreads();
    m = fmaxf(fmaxf(redm[0], redm[1]), fmaxf(redm[2], redm[3]));

    float s = 0.f;
#pragma unroll
    for (int i = 0; i < 8; ++i) {
        vals[i] = __expf(vals[i] - m);
        s += vals[i];
    }
#pragma unroll
    for (int off = 32; off; off >>= 1) s += __shfl_xor(s, off);
    if (lane == 0) reds[wave] = s;
    __syncthreads();
    s = reds[0] + reds[1] + reds[2] + reds[3];

    const float inv = 1.0f / s;
#pragma unroll
    for (int i = 0; i < 8; ++i) row[t + i * 256] = vals[i] * inv;
}

extern "C" void kernel_launch(void* const* d_in, const int* in_sizes, int n_in,
                              void* d_out, int out_size, void* d_ws, size_t ws_size,
                              hipStream_t stream)
{
    // Input order per setup_inputs():
    //   0: encoder_outputs          (B,S,D1) f32
    //   1: current_index            scalar int
    //   2: encoder_outputs_neighbor (B,N,D0) f32
    //   3: neighbor_num             scalar int (== N_, unused)
    //   4: W                        (D1,D0) f32
    //   5: b                        (D1,) f32  -- cancels in softmax, unused
    const float* enc     = (const float*)d_in[0];
    const int*   cur_idx = (const int*)d_in[1];
    const float* nb      = (const float*)d_in[2];
    const float* W       = (const float*)d_in[4];
    float*       out     = (float*)d_out;
    float*       v       = (float*)d_ws;   // B_*D0_*4 = 256 KB scratch

    prep_kernel<<<B_, D0_, 0, stream>>>(enc, cur_idx, W, v);
    logits_kernel<<<(B_ * N_) / 4, 256, 0, stream>>>(nb, v, out);
    softmax_kernel<<<B_, 256, 0, stream>>>(out);
}